// Round 2
// baseline (269.586 us; speedup 1.0000x reference)
//
#include <hip/hip_runtime.h>

// Problem constants
#define Vn 128
#define Bn 16
#define Nn 127
#define BTn 2048
#define RS 20   // padded LDS row stride (dwords): rows start 80B apart -> 16B aligned, 8 bank residues

__global__ __launch_bounds__(256, 4) void memnet_main(
    const float* __restrict__ node_fts, const float* __restrict__ edge_fts,
    const float* __restrict__ graph_fts, const float* __restrict__ adjm,
    const float* __restrict__ enc, const float* __restrict__ qb,
    const float* __restrict__ sb, const float* __restrict__ ob,
    const float* __restrict__ mc, const float* __restrict__ wout,
    const float* __restrict__ wfin, float* __restrict__ ret)
{
    __shared__ __align__(16) float sbL[128 * RS];
    __shared__ __align__(16) float obL[128 * RS];
    __shared__ __align__(16) float encL[32 * 16];
    __shared__ __align__(16) unsigned idxc[128 * 8];   // compacted indices, 32 u8/slot
    __shared__ float cjT[16 * 129];                    // gathered Cj, [e][compact slot]
    __shared__ float scoresL[128];
    __shared__ float probsL[128];
    __shared__ float probC[128];                       // compacted probs
    __shared__ float opart[128];
    __shared__ float xL[128];
    __shared__ int actmL[128];                         // compact slot -> m
    __shared__ unsigned char actF[128];
    __shared__ __align__(16) float uL[16];
    __shared__ float uoL[16], cCL[16];
    __shared__ float red[4];
    __shared__ unsigned long long wmaskL[4];
    __shared__ float k0L;

    const int t = threadIdx.x;
    const int bt = blockIdx.x;
    const int b = bt >> 7;     // batch
    const int i = bt & 127;    // node row (127 == graph-feature row)

    // ---- Phase A: stage tables + enc, read adj row, ballot ----
    for (int c = t; c < 512; c += 256) {
        int r = c >> 2, q = c & 3;
        float4 v = make_float4(0.f, 0.f, 0.f, 0.f);
        float4 w = make_float4(0.f, 0.f, 0.f, 0.f);
        if (r < 127) {
            v = *(const float4*)&sb[r * 16 + q * 4];
            w = *(const float4*)&ob[r * 16 + q * 4];
        }
        *(float4*)&sbL[r * RS + q * 4] = v;
        *(float4*)&obL[r * RS + q * 4] = w;
    }
    if (t < 128) *(float4*)&encL[t * 4] = *(const float4*)&enc[t * 4];
    bool act = false;
    if (t < 127 && i < 127) act = (adjm[(b * 127 + i) * 127 + t] != 0.f);
    unsigned long long bal = __ballot(act);
    if ((t & 63) == 0) wmaskL[t >> 6] = bal;
    if (t < 128) actF[t] = act ? 1 : 0;
    __syncthreads();   // S1

    // ---- Phase A2: compact list; u, encsum, constants ----
    const int nact = (int)(__popcll(wmaskL[0]) + __popcll(wmaskL[1]));
    if (act) {
        int wid = t >> 6;
        int base = (wid == 1) ? (int)__popcll(wmaskL[0]) : 0;
        int pos = base + (int)__popcll(wmaskL[wid] & ((1ull << (t & 63)) - 1ull));
        actmL[pos] = t;
    }
    if (t < 16) {
        float es = 0.f;
#pragma unroll
        for (int s = 0; s < 32; s++) es += encL[s * 16 + t];
        float ue = 0.f;
        for (int s = 0; s < 32; s++) {
            float qv = (i < 127) ? node_fts[(b * 127 + i) * 32 + s] : graph_fts[b * 32 + s];
            int qi = (int)qv; if (qi < 0) qi = 0;
            float w = (qi < 127) ? qb[qi * 16 + t] : 0.f;
            ue = fmaf(w, encL[s * 16 + t], ue);
        }
        uL[t] = ue;
        cCL[t] = obL[t] * es;                 // ob[0][e] * encsum[e]
        float kv = sbL[t] * es * ue;          // contribution of inactive-slot mem to score
        kv += __shfl_xor(kv, 1); kv += __shfl_xor(kv, 2);
        kv += __shfl_xor(kv, 4); kv += __shfl_xor(kv, 8);
        if (t == 0) k0L = kv;
    }
    __syncthreads();   // S2

    // ---- Phase B: stage compacted edge indices; init scores ----
    const int n8 = nact * 8;
    for (int c = t; c < n8; c += 256) {
        int m = actmL[c >> 3], q = c & 7;
        const float4 v = *(const float4*)&edge_fts[(((size_t)(b * 127 + i)) * 127 + m) * 32 + q * 4];
        idxc[c] = (unsigned)(int)v.x | ((unsigned)(int)v.y << 8)
                | ((unsigned)(int)v.z << 16) | ((unsigned)(int)v.w << 24);
    }
    if (t < 128) {
        float mdot = 0.f;
#pragma unroll
        for (int e = 0; e < 16; e++) mdot = fmaf(mc[t * 16 + e], uL[e], mdot);
        scoresL[t] = mdot + (actF[t] ? 0.f : k0L);
    }
    __syncthreads();   // S3

    // ---- Gather phase: quad (4 threads x 4e) per active slot ----
    const int eg4 = (t & 3) * 4;
    const int md = t >> 2;
    const float4 u4 = *(const float4*)&uL[eg4];
    for (int kk = md; kk < nact; kk += 64) {
        int m = actmL[kk];
        float4 aM = make_float4(0.f, 0.f, 0.f, 0.f);
        float4 aC = make_float4(0.f, 0.f, 0.f, 0.f);
#pragma unroll
        for (int sq = 0; sq < 8; sq++) {
            unsigned w = idxc[kk * 8 + sq];
#pragma unroll
            for (int j = 0; j < 4; j++) {
                int s = sq * 4 + j;
                int ix = (int)((w >> (8 * j)) & 0xFF);
                float4 eb = *(const float4*)&encL[s * 16 + eg4];
                float4 a  = *(const float4*)&sbL[ix * RS + eg4];
                float4 cc = *(const float4*)&obL[ix * RS + eg4];
                aM.x = fmaf(a.x, eb.x, aM.x); aM.y = fmaf(a.y, eb.y, aM.y);
                aM.z = fmaf(a.z, eb.z, aM.z); aM.w = fmaf(a.w, eb.w, aM.w);
                aC.x = fmaf(cc.x, eb.x, aC.x); aC.y = fmaf(cc.y, eb.y, aC.y);
                aC.z = fmaf(cc.z, eb.z, aC.z); aC.w = fmaf(cc.w, eb.w, aC.w);
            }
        }
        float p = aM.x * u4.x + aM.y * u4.y + aM.z * u4.z + aM.w * u4.w;
        p += __shfl_xor(p, 1); p += __shfl_xor(p, 2);
        if ((t & 3) == 0) scoresL[m] += p;   // each compact slot owned by one quad
        cjT[(eg4 + 0) * 129 + kk] = aC.x;
        cjT[(eg4 + 1) * 129 + kk] = aC.y;
        cjT[(eg4 + 2) * 129 + kk] = aC.z;
        cjT[(eg4 + 3) * 129 + kk] = aC.w;
    }
    __syncthreads();   // S4

    // ---- softmax over 128 slots ----
    {
        float v = (t < 128) ? scoresL[t] : -1e30f;
#pragma unroll
        for (int off = 32; off > 0; off >>= 1) v = fmaxf(v, __shfl_xor(v, off));
        if ((t & 63) == 0) red[t >> 6] = v;
        __syncthreads();
        float mx = fmaxf(fmaxf(red[0], red[1]), fmaxf(red[2], red[3]));
        float ex = (t < 128) ? __expf(scoresL[t] - mx) : 0.f;
        float sv = ex;
#pragma unroll
        for (int off = 32; off > 0; off >>= 1) sv += __shfl_xor(sv, off);
        __syncthreads();
        if ((t & 63) == 0) red[t >> 6] = sv;
        __syncthreads();
        float sum = red[0] + red[1] + red[2] + red[3];
        if (t < 128) probsL[t] = ex / sum;
    }
    __syncthreads();   // S5 (protect red reuse + probsL visibility)

    // ---- compact probs + sum of active probs ----
    {
        float pa = 0.f;
        if (t < 128) {
            pa = (t < nact) ? probsL[actmL[t]] : 0.f;
            probC[t] = pa;
        }
        float sv = pa;
#pragma unroll
        for (int off = 32; off > 0; off >>= 1) sv += __shfl_xor(sv, off);
        if ((t & 63) == 0) red[t >> 6] = sv;
    }
    __syncthreads();   // S6

    // ---- o[e] = sum over active compact slots + const for inactive mass ----
    if (t < 128) {
        int e = t & 15, ch = t >> 4;
        float acc = 0.f;
        for (int k = ch; k < nact; k += 8) acc += probC[k] * cjT[e * 129 + k];
        opart[t] = acc;
    }
    __syncthreads();   // S7
    if (t < 16) {
        float o = 0.f;
#pragma unroll
        for (int ch = 0; ch < 8; ch++) o += opart[ch * 16 + t];
        float sumAct = red[0] + red[1] + red[2] + red[3];
        uoL[t] = uL[t] + o + cCL[t] * (1.f - sumAct);
    }
    __syncthreads();   // S8

    // ---- x = relu((u+o) @ W_out) ----
    if (t < 128) {
        float acc = 0.f;
#pragma unroll
        for (int e = 0; e < 16; e++) acc = fmaf(uoL[e], wout[e * 128 + t], acc);
        xL[t] = fmaxf(acc, 0.f);
    }
    __syncthreads();   // S9

    // ---- ret = x @ W_fin, split across 256 threads ----
    float* part = sbL;   // sbL is dead; reuse as scratch
    {
        int v = t & 127, h = t >> 7;
        float acc = 0.f;
#pragma unroll
        for (int l0 = 0; l0 < 64; l0++) {
            int l = h * 64 + l0;
            acc = fmaf(xL[l], wfin[l * 128 + v], acc);
        }
        part[t] = acc;
    }
    __syncthreads();   // S10
    if (t < 128) ret[bt * 128 + t] = part[t] + part[t + 128];
}

// out[b,i,v] = ret[b,i,v] + ret[b,127,v]
__global__ void memnet_out(const float* __restrict__ ret, float* __restrict__ out)
{
    int idx = blockIdx.x * 256 + threadIdx.x;
    if (idx >= Bn * Nn * Vn) return;
    int v = idx & 127;
    int r = idx >> 7;          // b*127 + i
    int b = r / 127;
    int i = r - b * 127;
    out[idx] = ret[(b * 128 + i) * 128 + v] + ret[(b * 128 + 127) * 128 + v];
}

extern "C" void kernel_launch(void* const* d_in, const int* in_sizes, int n_in,
                              void* d_out, int out_size, void* d_ws, size_t ws_size,
                              hipStream_t stream)
{
    const float* node  = (const float*)d_in[0];
    const float* edge  = (const float*)d_in[1];
    const float* graph = (const float*)d_in[2];
    const float* adjm  = (const float*)d_in[3];
    // d_in[4] = hidden (unused)
    const float* enc   = (const float*)d_in[5];
    const float* qb    = (const float*)d_in[6];
    const float* sb    = (const float*)d_in[7];
    const float* ob    = (const float*)d_in[8];
    const float* mc    = (const float*)d_in[9];
    // d_in[10] = W_int (unused, num_hops == 1)
    const float* wout  = (const float*)d_in[11];
    const float* wfin  = (const float*)d_in[12];

    float* ws = (float*)d_ws;   // BTn * 128 floats = 1 MB scratch

    memnet_main<<<BTn, 256, 0, stream>>>(node, edge, graph, adjm, enc, qb,
                                         sb, ob, mc, wout, wfin, ws);
    const int total = Bn * Nn * Vn;
    memnet_out<<<(total + 255) / 256, 256, 0, stream>>>(ws, (float*)d_out);
}